// Round 19
// baseline (299.123 us; speedup 1.0000x reference)
//
#include <hip/hip_runtime.h>

#define NEG_SLOPE 0.2f

typedef __attribute__((ext_vector_type(8))) short short8;
typedef __attribute__((ext_vector_type(4))) float floatx4;
typedef unsigned short ushort_t;

#define BCAP 8192   // slots per bucket (mean fill 4096, >60 sigma headroom)

static __device__ __forceinline__ float leaky(float x){ return x > 0.f ? x : NEG_SLOPE * x; }

static __device__ __forceinline__ unsigned short bf16_rne(float x){
  unsigned u = __float_as_uint(x);
  unsigned r = (u + 0x7fffu + ((u >> 16) & 1u)) >> 16;
  return (unsigned short)r;
}
static __device__ __forceinline__ float bf16_to_f(unsigned short h){
  return __uint_as_float(((unsigned)h) << 16);
}

#define GLOAD_LDS16(g, l) \
  __builtin_amdgcn_global_load_lds((const __attribute__((address_space(1))) unsigned*)(g), \
                                   (__attribute__((address_space(3))) unsigned*)(l), 16, 0, 0)

// ---------------- K0: fused bucket-scatter + prep (disjoint block ranges) ----------------

__global__ __launch_bounds__(256) void fused0_kernel(const int* __restrict__ edges,
    const float* __restrict__ x,
    const float* __restrict__ W1, const float* __restrict__ W2, const float* __restrict__ W3,
    int* __restrict__ bucketCursor, uint2* __restrict__ pairs,
    ushort_t* __restrict__ xb,
    ushort_t* __restrict__ wt1, ushort_t* __restrict__ wt2, ushort_t* __restrict__ wt3,
    int N, int E, int gT){
  const int tid = threadIdx.x;
  if ((int)blockIdx.x < gT){
    // ---- bucket scatter ----
    __shared__ int hist[256], base[256], cur[256];
    const int t0 = blockIdx.x * 2048;
    hist[tid] = 0;
    __syncthreads();
    int myb[8], mys[8], myd[8];
    #pragma unroll
    for (int q = 0; q < 8; q++){
      int i = t0 + q * 256 + tid;
      int b = -1, s = 0, d = 0;
      if (i < E){
        s = edges[2*i]; d = edges[2*i + 1];
        b = d >> 8;
        atomicAdd(&hist[b], 1);
      }
      myb[q] = b; mys[q] = s; myd[q] = d;
    }
    __syncthreads();
    if (hist[tid] > 0) base[tid] = atomicAdd(&bucketCursor[tid], hist[tid]);
    cur[tid] = 0;
    __syncthreads();
    #pragma unroll
    for (int q = 0; q < 8; q++){
      int b = myb[q];
      if (b >= 0){
        int slot = base[b] + atomicAdd(&cur[b], 1);
        pairs[(size_t)b * BCAP + slot] = make_uint2((unsigned)mys[q], (unsigned)myd[q]);
      }
    }
  } else {
    // ---- prep (wprep + xprep) ----
    const int gsz  = 256 * 256;
    const int gtid = ((int)blockIdx.x - gT) * 256 + tid;
    for (int i = gtid; i < 131072; i += gsz){
      const float* W; ushort_t* tp; int K, Nw, idx;
      if (i < 32768)      { W = W1; tp = wt1; K = 128; Nw = 256; idx = i; }
      else if (i < 98304) { W = W2; tp = wt2; K = 256; Nw = 256; idx = i - 32768; }
      else                { W = W3; tp = wt3; K = 256; Nw = 128; idx = i - 98304; }
      int k = idx / Nw, n = idx - k * Nw;
      tp[(size_t)n * K + k] = bf16_rne(W[idx]);
    }
    int totx = N * 16;   // N*128/8
    for (int i = gtid; i < totx; i += gsz){
      int b2 = i * 8;
      float4 a = *(const float4*)(x + b2);
      float4 b = *(const float4*)(x + b2 + 4);
      short8 o;
      o[0] = (short)bf16_rne(a.x); o[1] = (short)bf16_rne(a.y);
      o[2] = (short)bf16_rne(a.z); o[3] = (short)bf16_rne(a.w);
      o[4] = (short)bf16_rne(b.x); o[5] = (short)bf16_rne(b.y);
      o[6] = (short)bf16_rne(b.z); o[7] = (short)bf16_rne(b.w);
      *(short8*)(xb + b2) = o;
    }
  }
}

// ---------------- K2: fused per-bucket hist + scans + row_ptr/inv + place ----------------

__global__ __launch_bounds__(256) void csr_build_place_kernel(const uint2* __restrict__ pairs,
    const int* __restrict__ bucketCursor, int* __restrict__ row_ptr,
    float* __restrict__ inv, int* __restrict__ col, int N, int B){
  __shared__ int hist[256];
  __shared__ int wt[4];
  __shared__ int bbase_s;
  __shared__ int rp[256];
  __shared__ int cur[256];
  const int tid = threadIdx.x;
  const int b = blockIdx.x;
  const int lane = tid & 63, w = tid >> 6;
  const int cnt = bucketCursor[b];
  hist[tid] = 0;
  cur[tid] = 0;
  __syncthreads();
  for (int i = tid; i < cnt; i += 256)
    atomicAdd(&hist[pairs[(size_t)b * BCAP + i].y & 255], 1);

  int bc = (tid < B) ? bucketCursor[tid] : 0;
  int sc = bc;
  #pragma unroll
  for (int o = 1; o < 64; o <<= 1){
    int q = __shfl_up(sc, o);
    if (lane >= o) sc += q;
  }
  if (lane == 63) wt[w] = sc;
  __syncthreads();
  {
    int base = 0;
    for (int j = 0; j < w; j++) base += wt[j];
    if (tid == b) bbase_s = base + sc - bc;
  }
  __syncthreads();

  int hv = hist[tid];
  int sr = hv;
  #pragma unroll
  for (int o = 1; o < 64; o <<= 1){
    int q = __shfl_up(sr, o);
    if (lane >= o) sr += q;
  }
  if (lane == 63) wt[w] = sr;
  __syncthreads();
  int rbase = bbase_s;
  for (int j = 0; j < w; j++) rbase += wt[j];
  int excl = rbase + sr - hv;
  rp[tid] = excl;
  int d = b * 256 + tid;
  if (d < N){
    row_ptr[d] = excl;
    inv[d] = (hv > 0) ? 1.0f / (float)hv : 0.0f;
    if (d == N - 1) row_ptr[N] = excl + hv;
  }
  __syncthreads();

  for (int i = tid; i < cnt; i += 256){
    uint2 p = pairs[(size_t)b * BCAP + i];
    int t = (int)p.y & 255;
    int pos = rp[t] + atomicAdd(&cur[t], 1);
    col[pos] = (int)p.x;
  }
}

// ---------------- K3: sort rows (one wave per row) ----------------

__global__ __launch_bounds__(256) void sortrows_kernel(const int* __restrict__ row_ptr,
                                                       int* __restrict__ col, int n){
  int gw = (blockIdx.x * 256 + threadIdx.x) >> 6;
  int lane = threadIdx.x & 63;
  if (gw >= n) return;
  int s = row_ptr[gw], e = row_ptr[gw + 1];
  int len = e - s;
  if (len <= 1) return;
  if (len <= 64){
    int v = (lane < len) ? col[s + lane] : 0x7fffffff;
    #pragma unroll
    for (int k = 2; k <= 64; k <<= 1){
      #pragma unroll
      for (int j = k >> 1; j > 0; j >>= 1){
        int o = __shfl_xor(v, j);
        bool dirUp = ((lane & k) == 0);
        bool takeMin = (((lane & j) == 0) == dirUp);
        v = takeMin ? min(v, o) : max(v, o);
      }
    }
    if (lane < len) col[s + lane] = v;
  } else if (lane == 0){
    for (int i = s + 1; i < e; ++i){
      int v = col[i];
      int j = i - 1;
      while (j >= s && col[j] > v){ col[j + 1] = col[j]; --j; }
      col[j + 1] = v;
    }
  }
}

// ---------------- MFMA GEMM (plain bf16 x bf16), FULL-WIDTH blocks ----------------
// N = 32*NF (NF=8 -> 256, NF=4 -> 128); one block covers all N columns, so A
// is read from HBM exactly ONCE (was twice with the 2-block-column grid).
// 4 waves: wrow = wid>>1 (64-row halves), wcol = wid&1 (16*NF-col halves).
// BK=32, LDS dbuf, one barrier/K-step. K-major granule-plane LDS.
// A buf: [4 gran][128 row]x16B (8KB). B buf: [4 gran][32*NF col]x16B (4*NF KB).
// MODE: 1 = bf16 out, leaky, bias masked by inv>0; 2 = bf16 out + bias.

template<int MODE, int NF>
__global__ __launch_bounds__(256) void gemm_mfma_kernel(
    const ushort_t* __restrict__ A, const ushort_t* __restrict__ Bt,
    const float* __restrict__ bias, const float* __restrict__ invv,
    ushort_t* __restrict__ Cp,
    int M, int K){
  constexpr int NCOL = 32 * NF;
  constexpr int BCH  = NCOL * 4;        // B chunks per buffer (16B each)
  __shared__ ushort_t ldsA[2][4096];
  __shared__ ushort_t ldsB[2][BCH * 8];
  const int tid  = threadIdx.x;
  const int lane = tid & 63;
  const int wid  = tid >> 6;
  const int wrow = wid >> 1;
  const int wcol = wid & 1;
  const int br = blockIdx.x * 128;

  floatx4 acc[4][NF];
  #pragma unroll
  for (int i = 0; i < 4; i++)
    #pragma unroll
    for (int j = 0; j < NF; j++) acc[i][j] = (floatx4){0.f, 0.f, 0.f, 0.f};

  auto STAGE = [&](int b, int k0){
    char* bufA = (char*)&ldsA[b][0];
    char* bufB = (char*)&ldsB[b][0];
    #pragma unroll
    for (int q = 0; q < 2; q++){
      int c = q * 256 + tid;
      int g = c >> 7, r = c & 127;
      int grow = br + r;
      if (grow < M)
        GLOAD_LDS16(A + (size_t)grow * K + k0 + g * 8,
                    bufA + (q * 256 + wid * 64) * 16);
    }
    #pragma unroll
    for (int q = 0; q < NF / 2; q++){
      int c = q * 256 + tid;
      int g = c / NCOL, colc = c % NCOL;
      GLOAD_LDS16(Bt + (size_t)colc * K + k0 + g * 8,
                  bufB + (q * 256 + wid * 64) * 16);
    }
  };

  auto COMPUTE = [&](int b){
    const ushort_t* bufA = &ldsA[b][0];
    const ushort_t* bufB = &ldsB[b][0];
    const int g = lane >> 4;
    short8 bh[NF];
    #pragma unroll
    for (int nf = 0; nf < NF; nf++)
      bh[nf] = *(const short8*)(bufB + (g * NCOL + wcol * (16 * NF) + nf * 16 + (lane & 15)) * 8);
    #pragma unroll
    for (int mf = 0; mf < 4; mf++){
      short8 ah = *(const short8*)(bufA + (g * 128 + wrow * 64 + mf * 16 + (lane & 15)) * 8);
      #pragma unroll
      for (int nf = 0; nf < NF; nf++)
        acc[mf][nf] = __builtin_amdgcn_mfma_f32_16x16x32_bf16(ah, bh[nf], acc[mf][nf], 0, 0, 0);
    }
  };

  const int nt = K >> 5;
  STAGE(0, 0);
  __syncthreads();
  for (int t = 0; t < nt; ++t){
    if (t + 1 < nt) STAGE((t + 1) & 1, (t + 1) << 5);
    COMPUTE(t & 1);
    __syncthreads();
  }

  const int r0 = br + wrow * 64;
  const int c0 = wcol * (16 * NF);
  #pragma unroll
  for (int nf = 0; nf < NF; nf++){
    int col = c0 + nf * 16 + (lane & 15);
    float bv = bias[col];
    #pragma unroll
    for (int mf = 0; mf < 4; mf++){
      int rbase = r0 + mf * 16 + ((lane >> 4) << 2);
      #pragma unroll
      for (int j = 0; j < 4; j++){
        int r = rbase + j;
        if (r >= M) continue;
        if (MODE == 1){
          float m = (invv[r] > 0.f) ? 1.f : 0.f;
          Cp[(size_t)r * NCOL + col] = bf16_rne(leaky(acc[mf][nf][j] + m * bv));
        } else {
          Cp[(size_t)r * NCOL + col] = bf16_rne(acc[mf][nf][j] + bv);
        }
      }
    }
  }
}

// ---------------- SpMM kernels (CSR gather, bf16 src, f32 accum) ----------------
// 16B/lane (ushort8) loads; per-column unroll-4 accumulator tree.

// xb (bf16 [n][128]) -> t (bf16 [n][128]); 4 rows/wave (16 lanes x 8 cols).
__global__ __launch_bounds__(256) void spmm128b_kernel(const ushort_t* __restrict__ xb,
    const int* __restrict__ row_ptr, const int* __restrict__ col,
    const float* __restrict__ inv, ushort_t* __restrict__ out, int n){
  int gw = (blockIdx.x * 256 + threadIdx.x) >> 4;
  int lane = threadIdx.x & 15;
  if (gw >= n) return;
  int s = row_ptr[gw], e = row_ptr[gw + 1];
  float ir = inv[gw];
  int off = lane * 8;
  floatx4 aL[4], aH[4];
  #pragma unroll
  for (int j = 0; j < 4; j++){ aL[j] = (floatx4){0,0,0,0}; aH[j] = (floatx4){0,0,0,0}; }
  int i = s;
  for (; i + 3 < e; i += 4){
    #pragma unroll
    for (int j = 0; j < 4; j++){
      int c = col[i + j];
      short8 u = *(const short8*)(xb + (size_t)c * 128 + off);
      aL[j][0] += bf16_to_f((ushort_t)u[0]); aL[j][1] += bf16_to_f((ushort_t)u[1]);
      aL[j][2] += bf16_to_f((ushort_t)u[2]); aL[j][3] += bf16_to_f((ushort_t)u[3]);
      aH[j][0] += bf16_to_f((ushort_t)u[4]); aH[j][1] += bf16_to_f((ushort_t)u[5]);
      aH[j][2] += bf16_to_f((ushort_t)u[6]); aH[j][3] += bf16_to_f((ushort_t)u[7]);
    }
  }
  for (; i < e; ++i){
    int c = col[i];
    short8 u = *(const short8*)(xb + (size_t)c * 128 + off);
    aL[0][0] += bf16_to_f((ushort_t)u[0]); aL[0][1] += bf16_to_f((ushort_t)u[1]);
    aL[0][2] += bf16_to_f((ushort_t)u[2]); aL[0][3] += bf16_to_f((ushort_t)u[3]);
    aH[0][0] += bf16_to_f((ushort_t)u[4]); aH[0][1] += bf16_to_f((ushort_t)u[5]);
    aH[0][2] += bf16_to_f((ushort_t)u[6]); aH[0][3] += bf16_to_f((ushort_t)u[7]);
  }
  short8 ov;
  #pragma unroll
  for (int k = 0; k < 4; k++){
    ov[k]     = (short)bf16_rne(((aL[0][k] + aL[1][k]) + (aL[2][k] + aL[3][k])) * ir);
    ov[4 + k] = (short)bf16_rne(((aH[0][k] + aH[1][k]) + (aH[2][k] + aH[3][k])) * ir);
  }
  *(short8*)(out + (size_t)gw * 128 + off) = ov;
}

// s2 (bf16 [n][256]) -> h2 (bf16 [n][256]); 2 rows/wave (32 lanes x 8 cols), leaky.
__global__ __launch_bounds__(256) void spmm256b_leaky_kernel(const ushort_t* __restrict__ sup,
    const int* __restrict__ row_ptr, const int* __restrict__ col,
    const float* __restrict__ inv, ushort_t* __restrict__ out, int n){
  int gw = (blockIdx.x * 256 + threadIdx.x) >> 5;
  int lane = threadIdx.x & 31;
  if (gw >= n) return;
  int s = row_ptr[gw], e = row_ptr[gw + 1];
  float ir = inv[gw];
  int off = lane * 8;
  floatx4 aL[4], aH[4];
  #pragma unroll
  for (int j = 0; j < 4; j++){ aL[j] = (floatx4){0,0,0,0}; aH[j] = (floatx4){0,0,0,0}; }
  int i = s;
  for (; i + 3 < e; i += 4){
    #pragma unroll
    for (int j = 0; j < 4; j++){
      int c = col[i + j];
      short8 u = *(const short8*)(sup + (size_t)c * 256 + off);
      aL[j][0] += bf16_to_f((ushort_t)u[0]); aL[j][1] += bf16_to_f((ushort_t)u[1]);
      aL[j][2] += bf16_to_f((ushort_t)u[2]); aL[j][3] += bf16_to_f((ushort_t)u[3]);
      aH[j][0] += bf16_to_f((ushort_t)u[4]); aH[j][1] += bf16_to_f((ushort_t)u[5]);
      aH[j][2] += bf16_to_f((ushort_t)u[6]); aH[j][3] += bf16_to_f((ushort_t)u[7]);
    }
  }
  for (; i < e; ++i){
    int c = col[i];
    short8 u = *(const short8*)(sup + (size_t)c * 256 + off);
    aL[0][0] += bf16_to_f((ushort_t)u[0]); aL[0][1] += bf16_to_f((ushort_t)u[1]);
    aL[0][2] += bf16_to_f((ushort_t)u[2]); aL[0][3] += bf16_to_f((ushort_t)u[3]);
    aH[0][0] += bf16_to_f((ushort_t)u[4]); aH[0][1] += bf16_to_f((ushort_t)u[5]);
    aH[0][2] += bf16_to_f((ushort_t)u[6]); aH[0][3] += bf16_to_f((ushort_t)u[7]);
  }
  short8 ov;
  #pragma unroll
  for (int k = 0; k < 4; k++){
    ov[k]     = (short)bf16_rne(leaky(((aL[0][k] + aL[1][k]) + (aL[2][k] + aL[3][k])) * ir));
    ov[4 + k] = (short)bf16_rne(leaky(((aH[0][k] + aH[1][k]) + (aH[2][k] + aH[3][k])) * ir));
  }
  *(short8*)(out + (size_t)gw * 256 + off) = ov;
}

// s3 (bf16 [n][128]) -> out f32 [n][128]; 4 rows/wave, inv + L2 row-normalize.
__global__ __launch_bounds__(256) void spmm_normb_kernel(const ushort_t* __restrict__ sup,
    const int* __restrict__ row_ptr, const int* __restrict__ col,
    const float* __restrict__ inv, float* __restrict__ out, int n){
  int gw = (blockIdx.x * 256 + threadIdx.x) >> 4;
  int lane = threadIdx.x & 15;
  if (gw >= n) return;
  int s = row_ptr[gw], e = row_ptr[gw + 1];
  float ir = inv[gw];
  int off = lane * 8;
  floatx4 aL[4], aH[4];
  #pragma unroll
  for (int j = 0; j < 4; j++){ aL[j] = (floatx4){0,0,0,0}; aH[j] = (floatx4){0,0,0,0}; }
  int i = s;
  for (; i + 3 < e; i += 4){
    #pragma unroll
    for (int j = 0; j < 4; j++){
      int c = col[i + j];
      short8 u = *(const short8*)(sup + (size_t)c * 128 + off);
      aL[j][0] += bf16_to_f((ushort_t)u[0]); aL[j][1] += bf16_to_f((ushort_t)u[1]);
      aL[j][2] += bf16_to_f((ushort_t)u[2]); aL[j][3] += bf16_to_f((ushort_t)u[3]);
      aH[j][0] += bf16_to_f((ushort_t)u[4]); aH[j][1] += bf16_to_f((ushort_t)u[5]);
      aH[j][2] += bf16_to_f((ushort_t)u[6]); aH[j][3] += bf16_to_f((ushort_t)u[7]);
    }
  }
  for (; i < e; ++i){
    int c = col[i];
    short8 u = *(const short8*)(sup + (size_t)c * 128 + off);
    aL[0][0] += bf16_to_f((ushort_t)u[0]); aL[0][1] += bf16_to_f((ushort_t)u[1]);
    aL[0][2] += bf16_to_f((ushort_t)u[2]); aL[0][3] += bf16_to_f((ushort_t)u[3]);
    aH[0][0] += bf16_to_f((ushort_t)u[4]); aH[0][1] += bf16_to_f((ushort_t)u[5]);
    aH[0][2] += bf16_to_f((ushort_t)u[6]); aH[0][3] += bf16_to_f((ushort_t)u[7]);
  }
  float v[8];
  #pragma unroll
  for (int k = 0; k < 4; k++){
    v[k]     = ((aL[0][k] + aL[1][k]) + (aL[2][k] + aL[3][k])) * ir;
    v[4 + k] = ((aH[0][k] + aH[1][k]) + (aH[2][k] + aH[3][k])) * ir;
  }
  float ss = ((v[0]*v[0] + v[1]*v[1]) + (v[2]*v[2] + v[3]*v[3]))
           + ((v[4]*v[4] + v[5]*v[5]) + (v[6]*v[6] + v[7]*v[7]));
  #pragma unroll
  for (int o = 8; o > 0; o >>= 1) ss += __shfl_xor(ss, o);
  float scale = 1.0f / fmaxf(sqrtf(ss), 1e-12f);
  float4 o0, o1;
  o0.x = v[0]*scale; o0.y = v[1]*scale; o0.z = v[2]*scale; o0.w = v[3]*scale;
  o1.x = v[4]*scale; o1.y = v[5]*scale; o1.z = v[6]*scale; o1.w = v[7]*scale;
  *(float4*)(out + (size_t)gw * 128 + off)     = o0;
  *(float4*)(out + (size_t)gw * 128 + off + 4) = o1;
}

// ---------------- launch ----------------

extern "C" void kernel_launch(void* const* d_in, const int* in_sizes, int n_in,
                              void* d_out, int out_size, void* d_ws, size_t ws_size,
                              hipStream_t stream){
  const float* x  = (const float*)d_in[0];
  const float* W1 = (const float*)d_in[1];
  const float* b1 = (const float*)d_in[2];
  const float* W2 = (const float*)d_in[3];
  const float* b2 = (const float*)d_in[4];
  const float* W3 = (const float*)d_in[5];
  const float* b3 = (const float*)d_in[6];
  const int* edges = (const int*)d_in[7];
  int N = in_sizes[0] / 128;
  int E = in_sizes[7] / 2;

  char* w = (char*)d_ws;
  size_t off = 0;
  auto alloc = [&](size_t bytes)->char*{
    char* p = w + off;
    off = (off + bytes + 255) & ~(size_t)255;
    return p;
  };
  int B = (N + 255) / 256;   // buckets; N<=65536 -> B<=256
  float* inv     = (float*)alloc((size_t)N * 4);
  int*   row_ptr = (int*)  alloc(((size_t)N + 1) * 4);
  int*   colidx  = (int*)  alloc((size_t)E * 4);
  int*   bucketCursor = (int*)alloc((size_t)B * 4);
  ushort_t* wt1 = (ushort_t*)alloc((size_t)128 * 256 * 2);
  ushort_t* wt2 = (ushort_t*)alloc((size_t)256 * 256 * 2);
  ushort_t* wt3 = (ushort_t*)alloc((size_t)256 * 128 * 2);
  char* slabA = alloc((size_t)N * 1024);   // 51.2 MB
  char* slabB = alloc((size_t)N * 1024);   // 51.2 MB

  ushort_t* xb     = (ushort_t*)slabA;                       // [N][128] bf16
  ushort_t* t_buf  = (ushort_t*)(slabA + (size_t)N * 256);   // [N][128] bf16
  ushort_t* s2_buf = (ushort_t*)(slabA + (size_t)N * 512);   // [N][256] bf16
  ushort_t* h1_buf = (ushort_t*)slabB;                       // [N][256] bf16
  ushort_t* h2_buf = (ushort_t*)(slabB + (size_t)N * 512);   // [N][256] bf16
  ushort_t* s3_buf = (ushort_t*)slabA;                       // [N][128] bf16 (aliases dead xb)
  uint2*    pairs  = (uint2*)slabB;   // bucket staging (dead before gemm1 writes h1)

  // CSR build: memset cursors -> fused(scatter || prep) -> csr_build+place -> sort
  hipMemsetAsync(bucketCursor, 0, (size_t)B * 4, stream);
  int gT = (E + 2047) / 2048;
  fused0_kernel<<<gT + 256, 256, 0, stream>>>(edges, x, W1, W2, W3, bucketCursor,
                                              pairs, xb, wt1, wt2, wt3, N, E, gT);
  csr_build_place_kernel<<<B, 256, 0, stream>>>(pairs, bucketCursor, row_ptr, inv,
                                                colidx, N, B);
  sortrows_kernel<<<(N * 64 + 255) / 256, 256, 0, stream>>>(row_ptr, colidx, N);

  int gm = (N + 127) / 128;
  int gS32 = (N * 32 + 255) / 256;   // 2 rows/wave
  int gS16 = (N * 16 + 255) / 256;   // 4 rows/wave

  // layer 1 (reordered): t = A_hat xb ; h1 = bf16(leaky(t@W1 + mask*b1))
  spmm128b_kernel<<<gS16, 256, 0, stream>>>(xb, row_ptr, colidx, inv, t_buf, N);
  gemm_mfma_kernel<1, 8><<<gm, 256, 0, stream>>>(t_buf, wt1, b1, inv, h1_buf, N, 128);
  // layer 2: s2 = bf16(h1@W2 + b2) ; h2 = bf16(leaky(A_hat s2))
  gemm_mfma_kernel<2, 8><<<gm, 256, 0, stream>>>(h1_buf, wt2, b2, nullptr, s2_buf, N, 256);
  spmm256b_leaky_kernel<<<gS32, 256, 0, stream>>>(s2_buf, row_ptr, colidx, inv, h2_buf, N);
  // layer 3: s3 = bf16(h2@W3 + b3) ; out = normalize(A_hat s3)
  gemm_mfma_kernel<2, 4><<<gm, 256, 0, stream>>>(h2_buf, wt3, b3, nullptr, s3_buf, N, 256);
  spmm_normb_kernel<<<gS16, 256, 0, stream>>>(s3_buf, row_ptr, colidx, inv, (float*)d_out, N);
}

// Round 20
// 266.604 us; speedup vs baseline: 1.1220x; 1.1220x over previous
//
#include <hip/hip_runtime.h>

#define NEG_SLOPE 0.2f

typedef __attribute__((ext_vector_type(8))) short short8;
typedef __attribute__((ext_vector_type(4))) float floatx4;
typedef unsigned short ushort_t;

#define BCAP 8192   // slots per bucket (mean fill 4096, >60 sigma headroom)

static __device__ __forceinline__ float leaky(float x){ return x > 0.f ? x : NEG_SLOPE * x; }

static __device__ __forceinline__ unsigned short bf16_rne(float x){
  unsigned u = __float_as_uint(x);
  unsigned r = (u + 0x7fffu + ((u >> 16) & 1u)) >> 16;
  return (unsigned short)r;
}
static __device__ __forceinline__ float bf16_to_f(unsigned short h){
  return __uint_as_float(((unsigned)h) << 16);
}

#define GLOAD_LDS16(g, l) \
  __builtin_amdgcn_global_load_lds((const __attribute__((address_space(1))) unsigned*)(g), \
                                   (__attribute__((address_space(3))) unsigned*)(l), 16, 0, 0)

// ---------------- K0: fused bucket-scatter + prep (disjoint block ranges) ----------------

__global__ __launch_bounds__(256) void fused0_kernel(const int* __restrict__ edges,
    const float* __restrict__ x,
    const float* __restrict__ W1, const float* __restrict__ W2, const float* __restrict__ W3,
    int* __restrict__ bucketCursor, uint2* __restrict__ pairs,
    ushort_t* __restrict__ xb,
    ushort_t* __restrict__ wt1, ushort_t* __restrict__ wt2, ushort_t* __restrict__ wt3,
    int N, int E, int gT){
  const int tid = threadIdx.x;
  if ((int)blockIdx.x < gT){
    // ---- bucket scatter ----
    __shared__ int hist[256], base[256], cur[256];
    const int t0 = blockIdx.x * 2048;
    hist[tid] = 0;
    __syncthreads();
    int myb[8], mys[8], myd[8];
    #pragma unroll
    for (int q = 0; q < 8; q++){
      int i = t0 + q * 256 + tid;
      int b = -1, s = 0, d = 0;
      if (i < E){
        s = edges[2*i]; d = edges[2*i + 1];
        b = d >> 8;
        atomicAdd(&hist[b], 1);
      }
      myb[q] = b; mys[q] = s; myd[q] = d;
    }
    __syncthreads();
    if (hist[tid] > 0) base[tid] = atomicAdd(&bucketCursor[tid], hist[tid]);
    cur[tid] = 0;
    __syncthreads();
    #pragma unroll
    for (int q = 0; q < 8; q++){
      int b = myb[q];
      if (b >= 0){
        int slot = base[b] + atomicAdd(&cur[b], 1);
        pairs[(size_t)b * BCAP + slot] = make_uint2((unsigned)mys[q], (unsigned)myd[q]);
      }
    }
  } else {
    // ---- prep (wprep + xprep) ----
    const int gsz  = 256 * 256;
    const int gtid = ((int)blockIdx.x - gT) * 256 + tid;
    for (int i = gtid; i < 131072; i += gsz){
      const float* W; ushort_t* tp; int K, Nw, idx;
      if (i < 32768)      { W = W1; tp = wt1; K = 128; Nw = 256; idx = i; }
      else if (i < 98304) { W = W2; tp = wt2; K = 256; Nw = 256; idx = i - 32768; }
      else                { W = W3; tp = wt3; K = 256; Nw = 128; idx = i - 98304; }
      int k = idx / Nw, n = idx - k * Nw;
      tp[(size_t)n * K + k] = bf16_rne(W[idx]);
    }
    int totx = N * 16;   // N*128/8
    for (int i = gtid; i < totx; i += gsz){
      int b2 = i * 8;
      float4 a = *(const float4*)(x + b2);
      float4 b = *(const float4*)(x + b2 + 4);
      short8 o;
      o[0] = (short)bf16_rne(a.x); o[1] = (short)bf16_rne(a.y);
      o[2] = (short)bf16_rne(a.z); o[3] = (short)bf16_rne(a.w);
      o[4] = (short)bf16_rne(b.x); o[5] = (short)bf16_rne(b.y);
      o[6] = (short)bf16_rne(b.z); o[7] = (short)bf16_rne(b.w);
      *(short8*)(xb + b2) = o;
    }
  }
}

// ---------------- K2: fused per-bucket hist + scans + row_ptr/inv + place ----------------

__global__ __launch_bounds__(256) void csr_build_place_kernel(const uint2* __restrict__ pairs,
    const int* __restrict__ bucketCursor, int* __restrict__ row_ptr,
    float* __restrict__ inv, int* __restrict__ col, int N, int B){
  __shared__ int hist[256];
  __shared__ int wt[4];
  __shared__ int bbase_s;
  __shared__ int rp[256];
  __shared__ int cur[256];
  const int tid = threadIdx.x;
  const int b = blockIdx.x;
  const int lane = tid & 63, w = tid >> 6;
  const int cnt = bucketCursor[b];
  hist[tid] = 0;
  cur[tid] = 0;
  __syncthreads();
  for (int i = tid; i < cnt; i += 256)
    atomicAdd(&hist[pairs[(size_t)b * BCAP + i].y & 255], 1);

  int bc = (tid < B) ? bucketCursor[tid] : 0;
  int sc = bc;
  #pragma unroll
  for (int o = 1; o < 64; o <<= 1){
    int q = __shfl_up(sc, o);
    if (lane >= o) sc += q;
  }
  if (lane == 63) wt[w] = sc;
  __syncthreads();
  {
    int base = 0;
    for (int j = 0; j < w; j++) base += wt[j];
    if (tid == b) bbase_s = base + sc - bc;
  }
  __syncthreads();

  int hv = hist[tid];
  int sr = hv;
  #pragma unroll
  for (int o = 1; o < 64; o <<= 1){
    int q = __shfl_up(sr, o);
    if (lane >= o) sr += q;
  }
  if (lane == 63) wt[w] = sr;
  __syncthreads();
  int rbase = bbase_s;
  for (int j = 0; j < w; j++) rbase += wt[j];
  int excl = rbase + sr - hv;
  rp[tid] = excl;
  int d = b * 256 + tid;
  if (d < N){
    row_ptr[d] = excl;
    inv[d] = (hv > 0) ? 1.0f / (float)hv : 0.0f;
    if (d == N - 1) row_ptr[N] = excl + hv;
  }
  __syncthreads();

  for (int i = tid; i < cnt; i += 256){
    uint2 p = pairs[(size_t)b * BCAP + i];
    int t = (int)p.y & 255;
    int pos = rp[t] + atomicAdd(&cur[t], 1);
    col[pos] = (int)p.x;
  }
}

// ---------------- K3: sort rows (one wave per row — full parallelism) ----------------

__global__ __launch_bounds__(256) void sortrows_kernel(const int* __restrict__ row_ptr,
                                                       int* __restrict__ col, int n){
  int gw = (blockIdx.x * 256 + threadIdx.x) >> 6;
  int lane = threadIdx.x & 63;
  if (gw >= n) return;
  int s = row_ptr[gw], e = row_ptr[gw + 1];
  int len = e - s;
  if (len <= 1) return;
  if (len <= 64){
    int v = (lane < len) ? col[s + lane] : 0x7fffffff;
    #pragma unroll
    for (int k = 2; k <= 64; k <<= 1){
      #pragma unroll
      for (int j = k >> 1; j > 0; j >>= 1){
        int o = __shfl_xor(v, j);
        bool dirUp = ((lane & k) == 0);
        bool takeMin = (((lane & j) == 0) == dirUp);
        v = takeMin ? min(v, o) : max(v, o);
      }
    }
    if (lane < len) col[s + lane] = v;
  } else if (lane == 0){
    for (int i = s + 1; i < e; ++i){
      int v = col[i];
      int j = i - 1;
      while (j >= s && col[j] > v){ col[j + 1] = col[j]; --j; }
      col[j + 1] = v;
    }
  }
}

// ---------------- MFMA GEMM (plain bf16 x bf16) ----------------
// 128x128 tile (split-column grid: blockIdx.y selects 128-col panel), 4 waves
// 2x2, BK=32, LDS dbuf, one barrier/K-step. K-major granule-plane LDS.
// 782 blocks at N=50k — parallelism-bound shape needs the 2-panel grid
// (R19's full-width 391-block variant was latency-exposed at 7.7% occupancy).
// MODE: 1 = bf16 out, leaky, bias masked by inv>0; 2 = bf16 out + bias.

template<int MODE>
__global__ __launch_bounds__(256) void gemm_mfma_kernel(
    const ushort_t* __restrict__ A, const ushort_t* __restrict__ Bt,
    const float* __restrict__ bias, const float* __restrict__ invv,
    ushort_t* __restrict__ Cp,
    int M, int K, int N){
  __shared__ ushort_t lds[2][8192];
  const int tid  = threadIdx.x;
  const int lane = tid & 63;
  const int wid  = tid >> 6;
  const int wrow = wid >> 1;
  const int wcol = wid & 1;
  const int br = blockIdx.x * 128;
  const int bc = blockIdx.y * 128;

  floatx4 acc[4][4];
  #pragma unroll
  for (int i = 0; i < 4; i++)
    #pragma unroll
    for (int j = 0; j < 4; j++) acc[i][j] = (floatx4){0.f, 0.f, 0.f, 0.f};

  auto STAGE = [&](int b, int k0){
    char* bufA = (char*)&lds[b][0];
    char* bufB = (char*)&lds[b][4096];
    #pragma unroll
    for (int q = 0; q < 2; q++){
      int c = q * 256 + tid;
      int g = c >> 7, r = c & 127;
      int grow = br + r;
      if (grow < M)
        GLOAD_LDS16(A + (size_t)grow * K + k0 + g * 8,
                    bufA + (q * 256 + wid * 64) * 16);
    }
    #pragma unroll
    for (int q = 0; q < 2; q++){
      int c = q * 256 + tid;
      int g = c >> 7, colc = c & 127;
      int gcol = bc + colc;
      GLOAD_LDS16(Bt + (size_t)gcol * K + k0 + g * 8,
                  bufB + (q * 256 + wid * 64) * 16);
    }
  };

  auto COMPUTE = [&](int b){
    const ushort_t* bufA = &lds[b][0];
    const ushort_t* bufB = &lds[b][4096];
    const int gsel = (lane >> 4) * 1024;
    short8 bh[4];
    #pragma unroll
    for (int nf = 0; nf < 4; nf++)
      bh[nf] = *(const short8*)(bufB + gsel + (wcol * 64 + nf * 16 + (lane & 15)) * 8);
    #pragma unroll
    for (int mf = 0; mf < 4; mf++){
      short8 ah = *(const short8*)(bufA + gsel + (wrow * 64 + mf * 16 + (lane & 15)) * 8);
      #pragma unroll
      for (int nf = 0; nf < 4; nf++)
        acc[mf][nf] = __builtin_amdgcn_mfma_f32_16x16x32_bf16(ah, bh[nf], acc[mf][nf], 0, 0, 0);
    }
  };

  const int nt = K >> 5;
  STAGE(0, 0);
  __syncthreads();
  for (int t = 0; t < nt; ++t){
    if (t + 1 < nt) STAGE((t + 1) & 1, (t + 1) << 5);
    COMPUTE(t & 1);
    __syncthreads();
  }

  const int r0 = br + wrow * 64;
  const int c0 = bc + wcol * 64;
  #pragma unroll
  for (int nf = 0; nf < 4; nf++){
    int col = c0 + nf * 16 + (lane & 15);
    float bv = bias[col];
    #pragma unroll
    for (int mf = 0; mf < 4; mf++){
      int rbase = r0 + mf * 16 + ((lane >> 4) << 2);
      #pragma unroll
      for (int j = 0; j < 4; j++){
        int r = rbase + j;
        if (r >= M) continue;
        if (MODE == 1){
          float m = (invv[r] > 0.f) ? 1.f : 0.f;
          Cp[(size_t)r * N + col] = bf16_rne(leaky(acc[mf][nf][j] + m * bv));
        } else {
          Cp[(size_t)r * N + col] = bf16_rne(acc[mf][nf][j] + bv);
        }
      }
    }
  }
}

// ---------------- SpMM kernels (CSR gather, bf16 src, f32 accum) ----------------
// 16B/lane (ushort8) loads; per-column unroll-4 accumulator tree.

// xb (bf16 [n][128]) -> t (bf16 [n][128]); 4 rows/wave (16 lanes x 8 cols).
__global__ __launch_bounds__(256) void spmm128b_kernel(const ushort_t* __restrict__ xb,
    const int* __restrict__ row_ptr, const int* __restrict__ col,
    const float* __restrict__ inv, ushort_t* __restrict__ out, int n){
  int gw = (blockIdx.x * 256 + threadIdx.x) >> 4;
  int lane = threadIdx.x & 15;
  if (gw >= n) return;
  int s = row_ptr[gw], e = row_ptr[gw + 1];
  float ir = inv[gw];
  int off = lane * 8;
  floatx4 aL[4], aH[4];
  #pragma unroll
  for (int j = 0; j < 4; j++){ aL[j] = (floatx4){0,0,0,0}; aH[j] = (floatx4){0,0,0,0}; }
  int i = s;
  for (; i + 3 < e; i += 4){
    #pragma unroll
    for (int j = 0; j < 4; j++){
      int c = col[i + j];
      short8 u = *(const short8*)(xb + (size_t)c * 128 + off);
      aL[j][0] += bf16_to_f((ushort_t)u[0]); aL[j][1] += bf16_to_f((ushort_t)u[1]);
      aL[j][2] += bf16_to_f((ushort_t)u[2]); aL[j][3] += bf16_to_f((ushort_t)u[3]);
      aH[j][0] += bf16_to_f((ushort_t)u[4]); aH[j][1] += bf16_to_f((ushort_t)u[5]);
      aH[j][2] += bf16_to_f((ushort_t)u[6]); aH[j][3] += bf16_to_f((ushort_t)u[7]);
    }
  }
  for (; i < e; ++i){
    int c = col[i];
    short8 u = *(const short8*)(xb + (size_t)c * 128 + off);
    aL[0][0] += bf16_to_f((ushort_t)u[0]); aL[0][1] += bf16_to_f((ushort_t)u[1]);
    aL[0][2] += bf16_to_f((ushort_t)u[2]); aL[0][3] += bf16_to_f((ushort_t)u[3]);
    aH[0][0] += bf16_to_f((ushort_t)u[4]); aH[0][1] += bf16_to_f((ushort_t)u[5]);
    aH[0][2] += bf16_to_f((ushort_t)u[6]); aH[0][3] += bf16_to_f((ushort_t)u[7]);
  }
  short8 ov;
  #pragma unroll
  for (int k = 0; k < 4; k++){
    ov[k]     = (short)bf16_rne(((aL[0][k] + aL[1][k]) + (aL[2][k] + aL[3][k])) * ir);
    ov[4 + k] = (short)bf16_rne(((aH[0][k] + aH[1][k]) + (aH[2][k] + aH[3][k])) * ir);
  }
  *(short8*)(out + (size_t)gw * 128 + off) = ov;
}

// s2 (bf16 [n][256]) -> h2 (bf16 [n][256]); 2 rows/wave (32 lanes x 8 cols), leaky.
__global__ __launch_bounds__(256) void spmm256b_leaky_kernel(const ushort_t* __restrict__ sup,
    const int* __restrict__ row_ptr, const int* __restrict__ col,
    const float* __restrict__ inv, ushort_t* __restrict__ out, int n){
  int gw = (blockIdx.x * 256 + threadIdx.x) >> 5;
  int lane = threadIdx.x & 31;
  if (gw >= n) return;
  int s = row_ptr[gw], e = row_ptr[gw + 1];
  float ir = inv[gw];
  int off = lane * 8;
  floatx4 aL[4], aH[4];
  #pragma unroll
  for (int j = 0; j < 4; j++){ aL[j] = (floatx4){0,0,0,0}; aH[j] = (floatx4){0,0,0,0}; }
  int i = s;
  for (; i + 3 < e; i += 4){
    #pragma unroll
    for (int j = 0; j < 4; j++){
      int c = col[i + j];
      short8 u = *(const short8*)(sup + (size_t)c * 256 + off);
      aL[j][0] += bf16_to_f((ushort_t)u[0]); aL[j][1] += bf16_to_f((ushort_t)u[1]);
      aL[j][2] += bf16_to_f((ushort_t)u[2]); aL[j][3] += bf16_to_f((ushort_t)u[3]);
      aH[j][0] += bf16_to_f((ushort_t)u[4]); aH[j][1] += bf16_to_f((ushort_t)u[5]);
      aH[j][2] += bf16_to_f((ushort_t)u[6]); aH[j][3] += bf16_to_f((ushort_t)u[7]);
    }
  }
  for (; i < e; ++i){
    int c = col[i];
    short8 u = *(const short8*)(sup + (size_t)c * 256 + off);
    aL[0][0] += bf16_to_f((ushort_t)u[0]); aL[0][1] += bf16_to_f((ushort_t)u[1]);
    aL[0][2] += bf16_to_f((ushort_t)u[2]); aL[0][3] += bf16_to_f((ushort_t)u[3]);
    aH[0][0] += bf16_to_f((ushort_t)u[4]); aH[0][1] += bf16_to_f((ushort_t)u[5]);
    aH[0][2] += bf16_to_f((ushort_t)u[6]); aH[0][3] += bf16_to_f((ushort_t)u[7]);
  }
  short8 ov;
  #pragma unroll
  for (int k = 0; k < 4; k++){
    ov[k]     = (short)bf16_rne(leaky(((aL[0][k] + aL[1][k]) + (aL[2][k] + aL[3][k])) * ir));
    ov[4 + k] = (short)bf16_rne(leaky(((aH[0][k] + aH[1][k]) + (aH[2][k] + aH[3][k])) * ir));
  }
  *(short8*)(out + (size_t)gw * 256 + off) = ov;
}

// s3 (bf16 [n][128]) -> out f32 [n][128]; 4 rows/wave, inv + L2 row-normalize.
__global__ __launch_bounds__(256) void spmm_normb_kernel(const ushort_t* __restrict__ sup,
    const int* __restrict__ row_ptr, const int* __restrict__ col,
    const float* __restrict__ inv, float* __restrict__ out, int n){
  int gw = (blockIdx.x * 256 + threadIdx.x) >> 4;
  int lane = threadIdx.x & 15;
  if (gw >= n) return;
  int s = row_ptr[gw], e = row_ptr[gw + 1];
  float ir = inv[gw];
  int off = lane * 8;
  floatx4 aL[4], aH[4];
  #pragma unroll
  for (int j = 0; j < 4; j++){ aL[j] = (floatx4){0,0,0,0}; aH[j] = (floatx4){0,0,0,0}; }
  int i = s;
  for (; i + 3 < e; i += 4){
    #pragma unroll
    for (int j = 0; j < 4; j++){
      int c = col[i + j];
      short8 u = *(const short8*)(sup + (size_t)c * 128 + off);
      aL[j][0] += bf16_to_f((ushort_t)u[0]); aL[j][1] += bf16_to_f((ushort_t)u[1]);
      aL[j][2] += bf16_to_f((ushort_t)u[2]); aL[j][3] += bf16_to_f((ushort_t)u[3]);
      aH[j][0] += bf16_to_f((ushort_t)u[4]); aH[j][1] += bf16_to_f((ushort_t)u[5]);
      aH[j][2] += bf16_to_f((ushort_t)u[6]); aH[j][3] += bf16_to_f((ushort_t)u[7]);
    }
  }
  for (; i < e; ++i){
    int c = col[i];
    short8 u = *(const short8*)(sup + (size_t)c * 128 + off);
    aL[0][0] += bf16_to_f((ushort_t)u[0]); aL[0][1] += bf16_to_f((ushort_t)u[1]);
    aL[0][2] += bf16_to_f((ushort_t)u[2]); aL[0][3] += bf16_to_f((ushort_t)u[3]);
    aH[0][0] += bf16_to_f((ushort_t)u[4]); aH[0][1] += bf16_to_f((ushort_t)u[5]);
    aH[0][2] += bf16_to_f((ushort_t)u[6]); aH[0][3] += bf16_to_f((ushort_t)u[7]);
  }
  float v[8];
  #pragma unroll
  for (int k = 0; k < 4; k++){
    v[k]     = ((aL[0][k] + aL[1][k]) + (aL[2][k] + aL[3][k])) * ir;
    v[4 + k] = ((aH[0][k] + aH[1][k]) + (aH[2][k] + aH[3][k])) * ir;
  }
  float ss = ((v[0]*v[0] + v[1]*v[1]) + (v[2]*v[2] + v[3]*v[3]))
           + ((v[4]*v[4] + v[5]*v[5]) + (v[6]*v[6] + v[7]*v[7]));
  #pragma unroll
  for (int o = 8; o > 0; o >>= 1) ss += __shfl_xor(ss, o);
  float scale = 1.0f / fmaxf(sqrtf(ss), 1e-12f);
  float4 o0, o1;
  o0.x = v[0]*scale; o0.y = v[1]*scale; o0.z = v[2]*scale; o0.w = v[3]*scale;
  o1.x = v[4]*scale; o1.y = v[5]*scale; o1.z = v[6]*scale; o1.w = v[7]*scale;
  *(float4*)(out + (size_t)gw * 128 + off)     = o0;
  *(float4*)(out + (size_t)gw * 128 + off + 4) = o1;
}

// ---------------- launch ----------------

extern "C" void kernel_launch(void* const* d_in, const int* in_sizes, int n_in,
                              void* d_out, int out_size, void* d_ws, size_t ws_size,
                              hipStream_t stream){
  const float* x  = (const float*)d_in[0];
  const float* W1 = (const float*)d_in[1];
  const float* b1 = (const float*)d_in[2];
  const float* W2 = (const float*)d_in[3];
  const float* b2 = (const float*)d_in[4];
  const float* W3 = (const float*)d_in[5];
  const float* b3 = (const float*)d_in[6];
  const int* edges = (const int*)d_in[7];
  int N = in_sizes[0] / 128;
  int E = in_sizes[7] / 2;

  char* w = (char*)d_ws;
  size_t off = 0;
  auto alloc = [&](size_t bytes)->char*{
    char* p = w + off;
    off = (off + bytes + 255) & ~(size_t)255;
    return p;
  };
  int B = (N + 255) / 256;   // buckets; N<=65536 -> B<=256
  float* inv     = (float*)alloc((size_t)N * 4);
  int*   row_ptr = (int*)  alloc(((size_t)N + 1) * 4);
  int*   colidx  = (int*)  alloc((size_t)E * 4);
  int*   bucketCursor = (int*)alloc((size_t)B * 4);
  ushort_t* wt1 = (ushort_t*)alloc((size_t)128 * 256 * 2);
  ushort_t* wt2 = (ushort_t*)alloc((size_t)256 * 256 * 2);
  ushort_t* wt3 = (ushort_t*)alloc((size_t)256 * 128 * 2);
  char* slabA = alloc((size_t)N * 1024);   // 51.2 MB
  char* slabB = alloc((size_t)N * 1024);   // 51.2 MB

  ushort_t* xb     = (ushort_t*)slabA;                       // [N][128] bf16
  ushort_t* t_buf  = (ushort_t*)(slabA + (size_t)N * 256);   // [N][128] bf16
  ushort_t* s2_buf = (ushort_t*)(slabA + (size_t)N * 512);   // [N][256] bf16
  ushort_t* h1_buf = (ushort_t*)slabB;                       // [N][256] bf16
  ushort_t* h2_buf = (ushort_t*)(slabB + (size_t)N * 512);   // [N][256] bf16
  ushort_t* s3_buf = (ushort_t*)slabA;                       // [N][128] bf16 (aliases dead xb)
  uint2*    pairs  = (uint2*)slabB;   // bucket staging (dead before gemm1 writes h1)

  // CSR build: memset cursors -> fused(scatter || prep) -> csr_build+place -> sort
  hipMemsetAsync(bucketCursor, 0, (size_t)B * 4, stream);
  int gT = (E + 2047) / 2048;
  fused0_kernel<<<gT + 256, 256, 0, stream>>>(edges, x, W1, W2, W3, bucketCursor,
                                              pairs, xb, wt1, wt2, wt3, N, E, gT);
  csr_build_place_kernel<<<B, 256, 0, stream>>>(pairs, bucketCursor, row_ptr, inv,
                                                colidx, N, B);
  sortrows_kernel<<<(N * 64 + 255) / 256, 256, 0, stream>>>(row_ptr, colidx, N);

  int gm = (N + 127) / 128;
  dim3 g12(gm, 2);
  dim3 g3 (gm, 1);
  int gS32 = (N * 32 + 255) / 256;   // 2 rows/wave
  int gS16 = (N * 16 + 255) / 256;   // 4 rows/wave

  // layer 1 (reordered): t = A_hat xb ; h1 = bf16(leaky(t@W1 + mask*b1))
  spmm128b_kernel<<<gS16, 256, 0, stream>>>(xb, row_ptr, colidx, inv, t_buf, N);
  gemm_mfma_kernel<1><<<g12, 256, 0, stream>>>(t_buf, wt1, b1, inv, h1_buf, N, 128, 256);
  // layer 2: s2 = bf16(h1@W2 + b2) ; h2 = bf16(leaky(A_hat s2))
  gemm_mfma_kernel<2><<<g12, 256, 0, stream>>>(h1_buf, wt2, b2, nullptr, s2_buf, N, 256, 256);
  spmm256b_leaky_kernel<<<gS32, 256, 0, stream>>>(s2_buf, row_ptr, colidx, inv, h2_buf, N);
  // layer 3: s3 = bf16(h2@W3 + b3) ; out = normalize(A_hat s3)
  gemm_mfma_kernel<2><<<g3, 256, 0, stream>>>(h2_buf, wt3, b3, nullptr, s3_buf, N, 256, 128);
  spmm_normb_kernel<<<gS16, 256, 0, stream>>>(s3_buf, row_ptr, colidx, inv, (float*)d_out, N);
}